// Round 9
// baseline (285.683 us; speedup 1.0000x reference)
//
#include <hip/hip_runtime.h>
#include <math.h>

#define CH 512
#define P 8
#define PLANE 4096   // 64*64
#define EPS 1e-5f

typedef float f4 __attribute__((ext_vector_type(4)));

__device__ __forceinline__ float leaky(float x) { return x >= 0.f ? x : 0.01f * x; }

__device__ __forceinline__ float wave_sum(float v) {
    #pragma unroll
    for (int off = 32; off; off >>= 1) v += __shfl_xor(v, off, 64);
    return v;
}

// ---------------- Kernel 1: prep (everything before main, one launch) --------
// blocks [0,16):   per-n: sd (LDS) + S scalar + bias GEMV (512 channels)
// blocks [16,32):  per-n: depthwise-kernel predictor conv (72 outputs)
// blocks [32,8224): per-(n,c) instance-norm stats (nc = blk-32)
__global__ __launch_bounds__(256) void prep_kernel(
    const float* __restrict__ style,     // [N,512,4,4]
    const float* __restrict__ content,   // [N,512,64,64]
    const float* __restrict__ dw_w,      // [8,512,2,2]
    const float* __restrict__ dw_b,      // [8]
    const float* __restrict__ pk_w,      // [8,512]
    const float* __restrict__ pk_b,      // [8]
    const float* __restrict__ pb_w,      // [512,512]
    const float* __restrict__ pb_b,      // [512]
    float* __restrict__ S_out,           // [N]
    float* __restrict__ d_pred,          // [N,72]
    float* __restrict__ bias_out,        // [N,512]
    float* __restrict__ mean_out,        // [N*512]
    float* __restrict__ rstd_out)        // [N*512]
{
    const int blk = blockIdx.x;
    const int t = threadIdx.x;
    const int wave = t >> 6, lane = t & 63;

    __shared__ __align__(16) float s_sd[512];
    __shared__ float red[4];
    __shared__ float ls[4], lq[4];

    if (blk < 16) {
        // ---- per-n: sd means -> S scalar -> bias GEMV ----
        const int n = blk;
        const float* sb = style + (size_t)n * 8192;
        #pragma unroll
        for (int qd = 0; qd < 2; ++qd) {
            int c = t + 256 * qd;
            const float4* sp = (const float4*)sb + c * 4;
            float4 a = sp[0], b = sp[1], d = sp[2], e = sp[3];
            float s = a.x + a.y + a.z + a.w + b.x + b.y + b.z + b.w
                    + d.x + d.y + d.z + d.w + e.x + e.y + e.z + e.w;
            s_sd[c] = s * (1.f / 16.f);
        }
        __syncthreads();
        // S = sum_o (pk_w[o] . sd + pk_b[o])
        float part = 0.f;
        #pragma unroll
        for (int o = 0; o < 8; ++o)
            part += pk_w[o * 512 + t] * s_sd[t]
                  + pk_w[o * 512 + t + 256] * s_sd[t + 256];
        part = wave_sum(part);
        if (lane == 0) red[wave] = part;
        __syncthreads();
        if (t == 0) {
            float S = red[0] + red[1] + red[2] + red[3];
            #pragma unroll
            for (int o = 0; o < 8; ++o) S += pk_b[o];
            S_out[n] = S;
        }
        // bias[c] = pb_w[c] . sd + pb_b[c]; each thread owns c = t, t+256.
        const f4* sdv = (const f4*)s_sd;
        #pragma unroll
        for (int qd = 0; qd < 2; ++qd) {
            int c = t + 256 * qd;
            const f4* pw = (const f4*)(pb_w + (size_t)c * 512);
            float acc = 0.f;
            #pragma unroll 8
            for (int k = 0; k < 128; ++k) {
                f4 w = pw[k], s = sdv[k];
                acc += w.x * s.x + w.y * s.y + w.z * s.z + w.w * s.w;
            }
            bias_out[n * 512 + c] = acc + pb_b[c];
        }
    } else if (blk < 32) {
        // ---- per-n: depthwise-kernel predictor: 72 outputs, 4 waves x 18 ----
        const int n = blk - 16;
        const float* sb = style + (size_t)n * 8192;
        const float4* wp = (const float4*)dw_w;
        for (int rr = 0; rr < 18; ++rr) {
            int r = wave * 18 + rr;
            int j = r / 9, pos = r % 9, y = pos / 3, x = pos % 3;
            float acc = 0.f;
            #pragma unroll
            for (int i = 0; i < 8; ++i) {
                int c = lane + 64 * i;
                float4 w = wp[j * 512 + c];
                const float* s = sb + c * 16 + y * 4 + x;
                acc += s[0] * w.x + s[1] * w.y + s[4] * w.z + s[5] * w.w;
            }
            acc = wave_sum(acc);
            if (lane == 0) d_pred[n * 72 + r] = leaky(acc + dw_b[j]);
        }
    } else {
        // ---- per-(n,c) instance-norm stats ----
        const int nc = blk - 32;
        const float4* base = (const float4*)(content + (size_t)nc * PLANE);
        float s = 0.f, sq = 0.f;
        #pragma unroll
        for (int k = 0; k < 4; ++k) {
            float4 v = base[k * 256 + t];
            s  += v.x + v.y + v.z + v.w;
            sq += v.x * v.x + v.y * v.y + v.z * v.z + v.w * v.w;
        }
        #pragma unroll
        for (int off = 32; off > 0; off >>= 1) {
            s  += __shfl_down(s, off, 64);
            sq += __shfl_down(sq, off, 64);
        }
        if (lane == 0) { ls[wave] = s; lq[wave] = sq; }
        __syncthreads();
        if (t == 0) {
            float S = ls[0] + ls[1] + ls[2] + ls[3];
            float Q = lq[0] + lq[1] + lq[2] + lq[3];
            float m = S * (1.f / 4096.f);
            float var = (Q - 4096.f * m * m) * (1.f / 4095.f);  // ddof=1
            mean_out[nc] = m;
            rstd_out[nc] = rsqrtf(var + EPS);
        }
    }
}

// ---------------- Kernel 2: fused conv + pointwise-collapse + IN ----------------
// Byte-identical to round-8's proven main: 2 output rows x 4 cols per thread,
// shfl x-halo, xc in registers, NT stores. grid = N * 64 * 2 = 2048.
__global__ __launch_bounds__(256) void main_kernel(
    const float* __restrict__ content,   // [N,512,64,64]
    const float* __restrict__ d_pred,    // [N,72]
    const float* __restrict__ S_in,      // [N]
    const float* __restrict__ bias_in,   // [N,512]
    const float* __restrict__ mean_in,   // [N*512]
    const float* __restrict__ rstd_in,   // [N*512]
    float* __restrict__ out)             // [N,512,64,64]
{
    const int b    = blockIdx.x;
    const int tile = b & 1;
    const int g    = (b >> 1) & 63;
    const int n    = b >> 7;
    const int t  = threadIdx.x;
    const int tx = t & 15, ty = t >> 4;
    const int h0 = tile * 32 + ty * 2;   // this thread's two rows: h0, h0+1
    const int x0 = tx * 4;

    __shared__ float s_d[72];
    __shared__ float s_S;
    __shared__ float s_bias[8], s_mean[8], s_rstd[8];
    if (t < 72) s_d[t] = d_pred[n * 72 + t];
    if (t == 80) s_S = S_in[n];
    if (t >= 88 && t < 96) {
        int o = t - 88;
        int c = n * 512 + g * 8 + o;
        s_bias[o] = bias_in[c];
        s_mean[o] = mean_in[c];
        s_rstd[o] = rstd_in[c];
    }
    __syncthreads();

    const float* cbase = content + (size_t)(n * 512 + g * 8) * PLANE;
    float D00 = 0.f, D01 = 0.f, D02 = 0.f, D03 = 0.f;   // row h0
    float D10 = 0.f, D11 = 0.f, D12 = 0.f, D13 = 0.f;   // row h0+1
    f4 xc[8][2];   // center taps for both rows, all 8 channels

    #pragma unroll
    for (int j = 0; j < 8; ++j) {
        const float* cj = cbase + j * PLANE;
        f4 v[4];
        float xm[4], xp[4];
        #pragma unroll
        for (int k = 0; k < 4; ++k) {     // input rows h0-1 .. h0+2
            int y = h0 - 1 + k;
            int ry = y < 0 ? 1 : (y > 63 ? 62 : y);   // reflect pad
            v[k] = *(const f4*)(cj + ry * 64 + x0);
            float lv = __shfl_up(v[k].w, 1, 64);
            float rv = __shfl_down(v[k].x, 1, 64);
            xm[k] = (tx == 0)  ? v[k].y : lv;   // x=-1 -> 1
            xp[k] = (tx == 15) ? v[k].z : rv;   // x=64 -> 62
        }
        xc[j][0] = v[1];
        xc[j][1] = v[2];
        #pragma unroll
        for (int r = 0; r < 3; ++r) {
            const float w0 = s_d[j * 9 + r * 3 + 0];
            const float w1 = s_d[j * 9 + r * 3 + 1];
            const float w2 = s_d[j * 9 + r * 3 + 2];
            D00 += w0 * xm[r]     + w1 * v[r].x   + w2 * v[r].y;
            D01 += w0 * v[r].x    + w1 * v[r].y   + w2 * v[r].z;
            D02 += w0 * v[r].y    + w1 * v[r].z   + w2 * v[r].w;
            D03 += w0 * v[r].z    + w1 * v[r].w   + w2 * xp[r];
            D10 += w0 * xm[r+1]   + w1 * v[r+1].x + w2 * v[r+1].y;
            D11 += w0 * v[r+1].x  + w1 * v[r+1].y + w2 * v[r+1].z;
            D12 += w0 * v[r+1].y  + w1 * v[r+1].z + w2 * v[r+1].w;
            D13 += w0 * v[r+1].z  + w1 * v[r+1].w + w2 * xp[r+1];
        }
    }

    const float S = s_S;
    const float P00 = D00 * S, P01 = D01 * S, P02 = D02 * S, P03 = D03 * S;
    const float P10 = D10 * S, P11 = D11 * S, P12 = D12 * S, P13 = D13 * S;
    float* obase = out + (size_t)(n * 512 + g * 8) * PLANE + h0 * 64 + x0;
    #pragma unroll
    for (int o = 0; o < 8; ++o) {
        float bb = s_bias[o], m = s_mean[o], rs = s_rstd[o];
        f4 r0, r1;
        r0.x = (xc[o][0].x - m) * rs * leaky(P00 + bb);
        r0.y = (xc[o][0].y - m) * rs * leaky(P01 + bb);
        r0.z = (xc[o][0].z - m) * rs * leaky(P02 + bb);
        r0.w = (xc[o][0].w - m) * rs * leaky(P03 + bb);
        r1.x = (xc[o][1].x - m) * rs * leaky(P10 + bb);
        r1.y = (xc[o][1].y - m) * rs * leaky(P11 + bb);
        r1.z = (xc[o][1].z - m) * rs * leaky(P12 + bb);
        r1.w = (xc[o][1].w - m) * rs * leaky(P13 + bb);
        __builtin_nontemporal_store(r0, (f4*)(obase + o * PLANE));
        __builtin_nontemporal_store(r1, (f4*)(obase + o * PLANE + 64));
    }
}

extern "C" void kernel_launch(void* const* d_in, const int* in_sizes, int n_in,
                              void* d_out, int out_size, void* d_ws, size_t ws_size,
                              hipStream_t stream) {
    const float* style   = (const float*)d_in[0];
    const float* content = (const float*)d_in[1];
    const float* dw_w    = (const float*)d_in[2];
    const float* dw_b    = (const float*)d_in[3];
    const float* pk_w    = (const float*)d_in[4];
    const float* pk_b    = (const float*)d_in[5];
    const float* pb_w    = (const float*)d_in[6];
    const float* pb_b    = (const float*)d_in[7];
    float* out = (float*)d_out;
    float* ws  = (float*)d_ws;

    const int N = 16;
    float* d_pred  = ws;                  // N*72
    float* S_ws    = d_pred + N * 72;     // N
    float* bias_ws = S_ws + N;            // N*512
    float* mean_ws = bias_ws + N * 512;   // N*512
    float* rstd_ws = mean_ws + N * 512;   // N*512

    prep_kernel<<<32 + N * 512, 256, 0, stream>>>(
        style, content, dw_w, dw_b, pk_w, pk_b, pb_w, pb_b,
        S_ws, d_pred, bias_ws, mean_ws, rstd_ws);
    main_kernel<<<N * 64 * 2, 256, 0, stream>>>(content, d_pred, S_ws, bias_ws,
                                                mean_ws, rstd_ws, out);
}